// Round 3
// baseline (1259.237 us; speedup 1.0000x reference)
//
#include <hip/hip_runtime.h>

// Linear3Bit: out = x @ W^T + bias, W dequantized from 3-bit groups.
// M=16384 (8*2048), N=OUT=4096, K=IN=4096.
//
// DTYPE NOTE (hard-won): the harness promotes the reference's float16 inputs
// (weight_scales, bias) to FLOAT32 on device. Evidence: reading them as fp16
// gave garbage capped at 6.5e4 (fp16 max); as bf16, garbage capped ~3e21
// (bf16 range) — signature of 2-byte windows into fp32 data. Read as float*.
//
// Pipeline:
//   1) dequant_kernel: packed int32 (2x3bit/byte) -> bf16 W [N,K] row-major
//   2) convx_kernel:   x fp32 -> bf16 [M,K]            (if ws_size allows)
//   3) gemm_kernel:    m97-style 128x128 tile, BK=64, 16x16x32 bf16 MFMA,
//                      global_load_lds width=16 staging, bias fused in epilogue.

#define K_DIM 4096
#define N_DIM 4096
#define BM 128
#define BN 128
#define BK 64

typedef __bf16 bf16_t;
typedef __bf16 bf16x8 __attribute__((ext_vector_type(8)));
typedef float f32x4 __attribute__((ext_vector_type(4)));

// async global->LDS, 16B per lane; LDS dest is wave-uniform base + lane*16
__device__ __forceinline__ void gload16(const void* g, void* l) {
    __builtin_amdgcn_global_load_lds(
        (const __attribute__((address_space(1))) unsigned int*)g,
        (__attribute__((address_space(3))) unsigned int*)l, 16, 0, 0);
}

// ---------------- dequant: 4 packed int32 -> 8 bf16 weights per thread ----------------
__global__ __launch_bounds__(256) void dequant_kernel(const int4* __restrict__ wp4,
                                                      const float* __restrict__ scales,
                                                      bf16x8* __restrict__ W) {
    const int t = blockIdx.x * 256 + threadIdx.x;      // 0 .. 2097151
    const int4 p = wp4[t];
    const float s = scales[t >> 2];                    // 4 threads per group of 32
    const float c = 2.0f / 7.0f;
    int v[4] = {p.x, p.y, p.z, p.w};
    bf16x8 o;
#pragma unroll
    for (int i = 0; i < 4; ++i) {
        float w0 = fmaf((float)(v[i] & 7), c, -1.0f) * s;        // low 3 bits -> even pos
        float w1 = fmaf((float)((v[i] >> 3) & 7), c, -1.0f) * s; // bits 3..5  -> odd pos
        o[2 * i]     = (__bf16)w0;
        o[2 * i + 1] = (__bf16)w1;
    }
    W[t] = o;  // flat weight index t*8 == group*32 + pos (row-major [N,K])
}

// ---------------- x fp32 -> bf16, 8 elems/thread ----------------
__global__ __launch_bounds__(256) void convx_kernel(const float4* __restrict__ X4,
                                                    bf16x8* __restrict__ Xb) {
    const int t = blockIdx.x * 256 + threadIdx.x;
    float4 a = X4[2 * t];
    float4 b = X4[2 * t + 1];
    bf16x8 o;
    o[0] = (__bf16)a.x; o[1] = (__bf16)a.y; o[2] = (__bf16)a.z; o[3] = (__bf16)a.w;
    o[4] = (__bf16)b.x; o[5] = (__bf16)b.y; o[6] = (__bf16)b.z; o[7] = (__bf16)b.w;
    Xb[t] = o;
}

// ---------------- GEMM: C[M,N] = A[M,K] * B[N,K]^T + bias ----------------
// PRE=true : A is preconverted bf16, staged via global_load_lds
// PRE=false: A is fp32, converted to bf16 during manual LDS staging (ws too small)
template <bool PRE>
__global__ __launch_bounds__(256) void gemm_kernel(const void* __restrict__ Ap,
                                                   const bf16_t* __restrict__ B,
                                                   const float* __restrict__ bias,
                                                   float* __restrict__ C) {
    __shared__ __align__(16) bf16_t As[BM * BK];  // 16 KB, row-major [row][BK]
    __shared__ __align__(16) bf16_t Bs[BN * BK];  // 16 KB

    const int tid  = threadIdx.x;
    const int lane = tid & 63;
    const int wv   = tid >> 6;          // 4 waves
    const int wm   = (wv & 1) * 64;     // wave's 64x64 quadrant
    const int wn   = (wv >> 1) * 64;
    const int m0   = blockIdx.y * BM;
    const int n0   = blockIdx.x * BN;

    f32x4 acc[4][4];
#pragma unroll
    for (int i = 0; i < 4; ++i)
#pragma unroll
        for (int j = 0; j < 4; ++j) acc[i][j] = {0.f, 0.f, 0.f, 0.f};

    const int r8   = lane >> 3;        // staging: row within 8-row chunk
    const int kc   = (lane & 7) * 8;   // staging: elem offset in row (16B granules)
    const int mrow = lane & 15;        // mfma frag: row/col within 16
    const int quad = lane >> 4;        // mfma frag: k-group

    for (int k0 = 0; k0 < K_DIM; k0 += BK) {
        __syncthreads();  // previous iter's compute done before LDS overwrite
        if (PRE) {
            const bf16_t* A = (const bf16_t*)Ap;
#pragma unroll
            for (int c = 0; c < 4; ++c) {
                const int rowb = wv * 32 + c * 8;  // wave-uniform 8-row chunk
                gload16(A + (size_t)(m0 + rowb + r8) * K_DIM + k0 + kc, &As[rowb * BK]);
                gload16(B + (size_t)(n0 + rowb + r8) * K_DIM + k0 + kc, &Bs[rowb * BK]);
            }
        } else {
            const float* A = (const float*)Ap;
            const int row = tid >> 1;
            const int kh  = (tid & 1) * 32;
            const float4* ga = (const float4*)(A + (size_t)(m0 + row) * K_DIM + k0 + kh);
            bf16x8* dst = (bf16x8*)&As[row * BK + kh];
#pragma unroll
            for (int c = 0; c < 4; ++c) {
                float4 u = ga[2 * c];
                float4 v = ga[2 * c + 1];
                bf16x8 o;
                o[0] = (__bf16)u.x; o[1] = (__bf16)u.y; o[2] = (__bf16)u.z; o[3] = (__bf16)u.w;
                o[4] = (__bf16)v.x; o[5] = (__bf16)v.y; o[6] = (__bf16)v.z; o[7] = (__bf16)v.w;
                dst[c] = o;
            }
#pragma unroll
            for (int c = 0; c < 4; ++c) {
                const int rowb = wv * 32 + c * 8;
                gload16(B + (size_t)(n0 + rowb + r8) * K_DIM + k0 + kc, &Bs[rowb * BK]);
            }
        }
        __syncthreads();  // drains vmcnt -> global_load_lds complete

#pragma unroll
        for (int kk = 0; kk < BK; kk += 32) {
            bf16x8 af[4], bfr[4];
#pragma unroll
            for (int i = 0; i < 4; ++i)
                af[i] = *(const bf16x8*)&As[(wm + i * 16 + mrow) * BK + kk + quad * 8];
#pragma unroll
            for (int j = 0; j < 4; ++j)
                bfr[j] = *(const bf16x8*)&Bs[(wn + j * 16 + mrow) * BK + kk + quad * 8];
#pragma unroll
            for (int i = 0; i < 4; ++i)
#pragma unroll
                for (int j = 0; j < 4; ++j)
                    acc[i][j] = __builtin_amdgcn_mfma_f32_16x16x32_bf16(af[i], bfr[j],
                                                                        acc[i][j], 0, 0, 0);
        }
    }

    // epilogue: C/D layout col = lane&15, row = (lane>>4)*4 + reg  [guide §3, m89-verified]
    const int col   = lane & 15;
    const int rbase = (lane >> 4) * 4;
#pragma unroll
    for (int j = 0; j < 4; ++j) {
        const int n  = n0 + wn + j * 16 + col;
        const float bn = bias[n];
#pragma unroll
        for (int i = 0; i < 4; ++i) {
            const size_t base = (size_t)(m0 + wm + i * 16 + rbase) * N_DIM + n;
#pragma unroll
            for (int r = 0; r < 4; ++r)
                C[base + (size_t)r * N_DIM] = acc[i][j][r] + bn;
        }
    }
}

extern "C" void kernel_launch(void* const* d_in, const int* in_sizes, int n_in,
                              void* d_out, int out_size, void* d_ws, size_t ws_size,
                              hipStream_t stream) {
    const float* x      = (const float*)d_in[0];
    const int*   wp     = (const int*)d_in[1];
    const float* scales = (const float*)d_in[2];   // fp16 in ref -> fp32 on device
    const float* bias   = (const float*)d_in[3];   // fp16 in ref -> fp32 on device
    float*       out    = (float*)d_out;

    const int M = in_sizes[0] / K_DIM;  // 16384

    bf16_t* Wb = (bf16_t*)d_ws;
    const size_t wbytes = (size_t)N_DIM * K_DIM * sizeof(bf16_t);          // 32 MB
    bf16_t* Xb = (bf16_t*)((char*)d_ws + wbytes);
    const size_t need = wbytes + (size_t)M * K_DIM * sizeof(bf16_t);       // +128 MB

    // 1) dequant weights -> bf16 [N,K]
    dequant_kernel<<<(N_DIM * K_DIM / 8) / 256, 256, 0, stream>>>(
        (const int4*)wp, scales, (bf16x8*)Wb);

    dim3 grid(N_DIM / BN, M / BM);  // (32, 128)
    if (ws_size >= need) {
        // 2) x -> bf16
        convx_kernel<<<((size_t)M * K_DIM / 8) / 256, 256, 0, stream>>>(
            (const float4*)x, (bf16x8*)Xb);
        // 3) GEMM
        gemm_kernel<true><<<grid, 256, 0, stream>>>(Xb, Wb, bias, out);
    } else {
        gemm_kernel<false><<<grid, 256, 0, stream>>>(x, Wb, bias, out);
    }
}